// Round 6
// baseline (1967.237 us; speedup 1.0000x reference)
//
#include <hip/hip_runtime.h>
#include <hip/hip_bf16.h>
#include <stdint.h>

#define NN   50000
#define EE   800000
#define RR   8
#define CIN  512
#define CHID 256
#define COUT 512
#define SEGS (RR * NN)
#define MHALF 25000
#define K2   2304              // 8*CHID + CHID (relations + root)
#define K2S  2048              // split point: below = G2, above = h

typedef __bf16 bf16x8 __attribute__((ext_vector_type(8)));
typedef __bf16 bf16x4 __attribute__((ext_vector_type(4)));
typedef float  f32x4  __attribute__((ext_vector_type(4)));

constexpr int SCAN_BS = 256, SCAN_ITEMS = 4, SCAN_CHUNK = SCAN_BS * SCAN_ITEMS; // 1024
constexpr int SCAN_NB = (SEGS + SCAN_CHUNK - 1) / SCAN_CHUNK;                   // 391

__device__ __forceinline__ f32x4 mfma_bf16(bf16x8 a, bf16x8 b, f32x4 c) {
    return __builtin_amdgcn_mfma_f32_16x16x32_bf16(a, b, c, 0, 0, 0);
}

__device__ __forceinline__ void gload_lds16(const void* g, void* l) {
    __builtin_amdgcn_global_load_lds((const __attribute__((address_space(1))) void*)g,
                                     (__attribute__((address_space(3))) void*)l, 16, 0, 0);
}

// ---------------- prep: split fp32 -> (hi, lo) bf16 ----------------
__global__ void cvt_split(const float* __restrict__ in, __bf16* __restrict__ hi,
                          __bf16* __restrict__ lo, int n4) {
    int i = blockIdx.x * blockDim.x + threadIdx.x;
    if (i >= n4) return;
    f32x4 v = ((const f32x4*)in)[i];
    bf16x4 h, l;
#pragma unroll
    for (int j = 0; j < 4; ++j) {
        __bf16 hj = (__bf16)v[j];
        h[j] = hj;
        l[j] = (__bf16)(v[j] - (float)hj);
    }
    ((bf16x4*)hi)[i] = h;
    ((bf16x4*)lo)[i] = l;
}

// transpose + split weights into B^T layout: dst[rel*relstride + col*Ktot + koffbase + rel*koffstride + k]
__global__ void wprep(const float* __restrict__ W, __bf16* __restrict__ hi,
                      __bf16* __restrict__ lo, int K0, int NC, int Ktot,
                      int koffbase, int koffstride, int relstride) {
    int r = blockIdx.z;
    int idx = blockIdx.x * blockDim.x + threadIdx.x;
    if (idx >= K0 * NC) return;
    int k = idx / NC, c = idx % NC;
    float v = W[(size_t)r * K0 * NC + idx];
    __bf16 h = (__bf16)v;
    size_t o = (size_t)r * relstride + (size_t)c * Ktot + koffbase + r * koffstride + k;
    hi[o] = h;
    lo[o] = (__bf16)(v - (float)h);
}

// ---------------- per-(rel,dst) edge counts ----------------
__global__ void count_edges(const int* __restrict__ et, const int* __restrict__ dst,
                            int* __restrict__ cnt) {
    int e = blockIdx.x * blockDim.x + threadIdx.x;
    if (e < EE) atomicAdd(&cnt[et[e] * NN + dst[e]], 1);
}

// ---------------- exclusive scan of cnt[SEGS] -> cursor (3-pass) ----------------
__global__ void scan_partial(const int* __restrict__ cnt, int* __restrict__ bsum) {
    __shared__ int lds[SCAN_BS];
    const int b = blockIdx.x, t = threadIdx.x;
    const int base = b * SCAN_CHUNK + t * SCAN_ITEMS;
    int s = 0;
#pragma unroll
    for (int j = 0; j < SCAN_ITEMS; ++j) {
        int i = base + j;
        if (i < SEGS) s += cnt[i];
    }
    lds[t] = s;
    __syncthreads();
    for (int off = SCAN_BS / 2; off > 0; off >>= 1) {
        if (t < off) lds[t] += lds[t + off];
        __syncthreads();
    }
    if (t == 0) bsum[b] = lds[0];
}

__global__ void scan_bsum(int* __restrict__ bsum) {
    __shared__ int lds[512];
    const int t = threadIdx.x;
    const int v = (t < SCAN_NB) ? bsum[t] : 0;
    lds[t] = v;
    __syncthreads();
    for (int off = 1; off < 512; off <<= 1) {
        int x = (t >= off) ? lds[t - off] : 0;
        __syncthreads();
        lds[t] += x;
        __syncthreads();
    }
    if (t < SCAN_NB) bsum[t] = lds[t] - v;   // exclusive
}

__global__ void scan_final(const int* __restrict__ cnt, const int* __restrict__ bsum,
                           int* __restrict__ cursor) {
    __shared__ int lds[SCAN_BS];
    const int b = blockIdx.x, t = threadIdx.x;
    const int base = b * SCAN_CHUNK + t * SCAN_ITEMS;
    int v[SCAN_ITEMS];
    int s = 0;
#pragma unroll
    for (int j = 0; j < SCAN_ITEMS; ++j) {
        int i = base + j;
        v[j] = (i < SEGS) ? cnt[i] : 0;
        s += v[j];
    }
    lds[t] = s;
    __syncthreads();
    for (int off = 1; off < SCAN_BS; off <<= 1) {
        int x = (t >= off) ? lds[t - off] : 0;
        __syncthreads();
        lds[t] += x;
        __syncthreads();
    }
    int run = lds[t] - s + bsum[b];
#pragma unroll
    for (int j = 0; j < SCAN_ITEMS; ++j) {
        int i = base + j;
        if (i < SEGS) cursor[i] = run;
        run += v[j];
    }
}

// ---------------- bucket fill: esrc sorted by (rel,dst) segment ----------------
// after this pass, cursor[s] == segment END offset (begin = end - cnt[s])
__global__ void bucket_fill(const int* __restrict__ src, const int* __restrict__ dst,
                            const int* __restrict__ et, int* __restrict__ cursor,
                            int* __restrict__ esrc) {
    int e = blockIdx.x * blockDim.x + threadIdx.x;
    if (e < EE) {
        int s = et[e] * NN + dst[e];
        int pos = atomicAdd(&cursor[s], 1);
        esrc[pos] = src[e];
    }
}

// ---------------- 256x256-tile split-bf16 MFMA GEMM, 8 waves, counted-vmcnt dbuf ----------------
// C[M,NC] = A[M,K] @ B^T[NC,K]^T, A = [A1 (k<K1) | A2 (k>=K1)], all hi/lo split (3-term).
// LDS K-tile = [256 rows][32 hi | 32 lo] bf16 per matrix, 64 KB/slot, 2 slots = 128 KB.
// Stage next tile (8 gload_lds) -> s_waitcnt vmcnt(8) (counted: next tile's loads stay in
// flight across the barrier) -> barrier -> consume -> lgkmcnt(0) -> barrier.
// Chunk-XOR LDS swizzle via pre-swizzled global source (linear gload_lds dest, rule #21).
// EPI 0: C=v;  EPI 3: C=v+bias[col].
template <int K, int K1, int SA1, int SA2, int NC, int EPI>
__global__ __launch_bounds__(512, 2) void gemm256(
    const __bf16* __restrict__ A1h, const __bf16* __restrict__ A1l,
    const __bf16* __restrict__ A2h, const __bf16* __restrict__ A2l,
    const __bf16* __restrict__ Bh, const __bf16* __restrict__ Bl,
    float* __restrict__ C, const float* __restrict__ bias, int M) {
    constexpr int NKT = K / 32;            // 32 real-K per tile
    constexpr int NT = NC / 256;
    __shared__ __bf16 lds[65536];          // 128 KB: sA[2][16384] | sB[2][16384]
    __bf16* sA = lds;
    __bf16* sB = lds + 32768;

    // bijective XCD-aware swizzle (m204)
    const int nwg = gridDim.x;
    const int orig = blockIdx.x;
    const int q8 = nwg >> 3, r8 = nwg & 7;
    const int xcd = orig & 7, lin = orig >> 3;
    const int wg = (xcd < r8 ? xcd * (q8 + 1) : r8 * (q8 + 1) + (xcd - r8) * q8) + lin;
    const int mtile = wg / NT, ntile = wg % NT;
    const int row0 = mtile * 256, col0 = ntile * 256;

    const int t = threadIdx.x;
    const int lane = t & 63;
    const int wid = t >> 6;
    const int wm = wid >> 2, wn = wid & 3;   // 2 x 4 waves; per-wave out = 128 x 64

    // ---- staging constants: dest (row = j*64 + t>>3, chunk = t&7), source chunk
    // s = c ^ ((row>>1)&7) = c ^ ((t>>4)&7); s<4 -> hi buffer col s*8, else lo ----
    const int sChunk = (t & 7) ^ ((t >> 4) & 7);
    const bool sLo = sChunk >= 4;
    const int scol = (sChunk & 3) * 8;
    int arow[4], brow[4];
#pragma unroll
    for (int j = 0; j < 4; ++j) {
        int r = row0 + j * 64 + (t >> 3);
        arow[j] = r < M ? r : M - 1;         // clamp tail rows (masked at store)
        brow[j] = col0 + j * 64 + (t >> 3);
    }
    const __bf16* Bb = sLo ? Bl : Bh;

    // ---- fragment-read constants: chunk' = k-chunk ^ ((row>>1)&7), lo = hi^4 ----
    const int fr = lane & 15;
    const int cHi = (lane >> 4) ^ ((lane >> 1) & 7);
    const int swzHi = cHi * 8;
    const int swzLo = (cHi ^ 4) * 8;

    f32x4 acc[8][4] = {};

    auto STAGE = [&](int slot, int kt) {
        const int k0 = kt * 32;
        const bool useA2 = (K1 < K) && (k0 >= K1);
        const __bf16* Ab = useA2 ? (sLo ? A2l : A2h) : (sLo ? A1l : A1h);
        const int astr = useA2 ? SA2 : SA1;
        const int ak = (useA2 ? k0 - K1 : k0) + scol;
        const int bk = k0 + scol;
        __bf16* dA = sA + slot * 16384 + t * 8;   // linear dest: thread t -> bytes [16t,16t+16)
        __bf16* dB = sB + slot * 16384 + t * 8;
#pragma unroll
        for (int j = 0; j < 4; ++j) {
            gload_lds16(Ab + (size_t)arow[j] * astr + ak, dA + j * 4096);
            gload_lds16(Bb + (size_t)brow[j] * K + bk, dB + j * 4096);
        }
    };

    STAGE(0, 0);
    for (int kt = 0; kt < NKT; ++kt) {
        const int slot = kt & 1;
        if (kt + 1 < NKT) {
            STAGE(slot ^ 1, kt + 1);
            asm volatile("s_waitcnt vmcnt(8)" ::: "memory");  // current tile landed; next in flight
        } else {
            asm volatile("s_waitcnt vmcnt(0)" ::: "memory");
        }
        __builtin_amdgcn_s_barrier();

        const __bf16* cA = sA + slot * 16384;
        const __bf16* cB = sB + slot * 16384;
        bf16x8 bh[4], bl[4];
#pragma unroll
        for (int n = 0; n < 4; ++n) {
            const __bf16* p = cB + (wn * 64 + n * 16 + fr) * 64;
            bh[n] = *(const bf16x8*)(p + swzHi);
            bl[n] = *(const bf16x8*)(p + swzLo);
        }
#pragma unroll
        for (int mp = 0; mp < 4; ++mp) {
            bf16x8 ah[2], al[2];
#pragma unroll
            for (int mm = 0; mm < 2; ++mm) {
                const __bf16* p = cA + (wm * 128 + mp * 32 + mm * 16 + fr) * 64;
                ah[mm] = *(const bf16x8*)(p + swzHi);
                al[mm] = *(const bf16x8*)(p + swzLo);
            }
            __builtin_amdgcn_s_setprio(1);
#pragma unroll
            for (int mm = 0; mm < 2; ++mm)
#pragma unroll
                for (int n = 0; n < 4; ++n) {
                    f32x4 c = acc[mp * 2 + mm][n];
                    c = mfma_bf16(ah[mm], bh[n], c);
                    c = mfma_bf16(al[mm], bh[n], c);
                    c = mfma_bf16(ah[mm], bl[n], c);
                    acc[mp * 2 + mm][n] = c;
                }
            __builtin_amdgcn_s_setprio(0);
        }
        asm volatile("s_waitcnt lgkmcnt(0)" ::: "memory");  // reads done before slot reuse
        __builtin_amdgcn_s_barrier();
    }

#pragma unroll
    for (int m = 0; m < 8; ++m)
#pragma unroll
        for (int n = 0; n < 4; ++n)
#pragma unroll
            for (int qq = 0; qq < 4; ++qq) {
                int row = row0 + wm * 128 + m * 16 + (lane >> 4) * 4 + qq;
                int col = col0 + wn * 64 + n * 16 + fr;
                if (row < M) {
                    size_t o = (size_t)row * NC + col;
                    float v = acc[m][n][qq];
                    if (EPI == 3) v += bias[col];
                    C[o] = v;
                }
            }
}

// ---------------- L1 gather (2 relations per pass): h_pre[d] += sum of both rel-means ----------------
__global__ void gather_l1_pair(const float* __restrict__ xW0, const float* __restrict__ xW1,
                               const int* __restrict__ esrc, const int* __restrict__ cursor,
                               const int* __restrict__ cnt, float* __restrict__ h_pre,
                               int rel0) {
    const int d = blockIdx.x * 4 + (threadIdx.x >> 6);
    if (d >= NN) return;
    const int lane = threadIdx.x & 63;
    const int s0 = rel0 * NN + d;
    const int s1 = s0 + NN;
    const int n0 = cnt[s0], n1 = cnt[s1];
    if ((n0 | n1) == 0) return;
    f32x4 v = {};
    if (n0 > 0) {
        const int end = cursor[s0];
        f32x4 t = {};
        for (int i = end - n0; i < end; ++i)
            t += ((const f32x4*)(xW0 + (size_t)esrc[i] * CHID))[lane];
        v += t * (1.0f / (float)n0);
    }
    if (n1 > 0) {
        const int end = cursor[s1];
        f32x4 t = {};
        for (int i = end - n1; i < end; ++i)
            t += ((const f32x4*)(xW1 + (size_t)esrc[i] * CHID))[lane];
        v += t * (1.0f / (float)n1);
    }
    ((f32x4*)(h_pre + (size_t)d * CHID))[lane] += v;
}

// ---------------- finish1: h = relu(h_pre) -> split bf16 hi/lo ----------------
__global__ void finish1(const float* __restrict__ h_pre, __bf16* __restrict__ hh,
                        __bf16* __restrict__ hl) {
    int i = blockIdx.x * blockDim.x + threadIdx.x;
    if (i >= NN * CHID / 4) return;
    f32x4 v = ((const f32x4*)h_pre)[i];
    bf16x4 a, b;
#pragma unroll
    for (int j = 0; j < 4; ++j) {
        float x = fmaxf(v[j], 0.0f);
        __bf16 h = (__bf16)x;
        a[j] = h;
        b[j] = (__bf16)(x - (float)h);
    }
    ((bf16x4*)hh)[i] = a;
    ((bf16x4*)hl)[i] = b;
}

// ---------------- L2 gather-aggregate: G2[dloc, rel*256+c] = mean_{seg(rel,d)} h[src,c] ----------------
// one wave per (rel, dloc) segment; nontemporal stores keep h L3-resident
__global__ void gather_g2(const __bf16* __restrict__ hh, const __bf16* __restrict__ hl,
                          const int* __restrict__ esrc, const int* __restrict__ cursor,
                          const int* __restrict__ cnt, __bf16* __restrict__ G2h,
                          __bf16* __restrict__ G2l, int half) {
    const int sidx = blockIdx.x * 4 + (threadIdx.x >> 6);
    if (sidx >= RR * MHALF) return;
    const int lane = threadIdx.x & 63;
    const int rel = sidx / MHALF;
    const int dloc = sidx % MHALF;
    const int d = half * MHALF + dloc;
    const int s = rel * NN + d;
    const int n = cnt[s];
    f32x4 v = {};
    if (n > 0) {
        const int end = cursor[s];
        for (int i = end - n; i < end; ++i) {
            const size_t ro = (size_t)esrc[i] * CHID + lane * 4;
            bf16x4 a = *(const bf16x4*)(hh + ro);
            bf16x4 b = *(const bf16x4*)(hl + ro);
#pragma unroll
            for (int j = 0; j < 4; ++j) v[j] += (float)a[j] + (float)b[j];
        }
        const float inv = 1.0f / (float)n;
#pragma unroll
        for (int j = 0; j < 4; ++j) v[j] *= inv;
    }
    union { __bf16 b[4]; unsigned long long u; } ph, pl;
#pragma unroll
    for (int j = 0; j < 4; ++j) {
        __bf16 h = (__bf16)v[j];
        ph.b[j] = h;
        pl.b[j] = (__bf16)(v[j] - (float)h);
    }
    const size_t o = (size_t)dloc * K2S + rel * CHID + lane * 4;
    __builtin_nontemporal_store(ph.u, (unsigned long long*)(G2h + o));
    __builtin_nontemporal_store(pl.u, (unsigned long long*)(G2l + o));
}

// ---------------- row-wise L2 normalize (one wave per 512-col row) ----------------
__global__ void l2norm(float* __restrict__ out) {
    int row = blockIdx.x * 4 + (threadIdx.x >> 6);
    int lane = threadIdx.x & 63;
    if (row >= NN) return;
    float* p = out + (size_t)row * COUT;
    f32x4 a = ((const f32x4*)p)[lane];
    f32x4 b = ((const f32x4*)p)[lane + 64];
    float ss = a[0] * a[0] + a[1] * a[1] + a[2] * a[2] + a[3] * a[3] +
               b[0] * b[0] + b[1] * b[1] + b[2] * b[2] + b[3] * b[3];
#pragma unroll
    for (int m = 32; m >= 1; m >>= 1) ss += __shfl_xor(ss, m, 64);
    const float s = 1.0f / fmaxf(sqrtf(ss), 1e-12f);
#pragma unroll
    for (int j = 0; j < 4; ++j) { a[j] *= s; b[j] *= s; }
    ((f32x4*)p)[lane] = a;
    ((f32x4*)p)[lane + 64] = b;
}

extern "C" void kernel_launch(void* const* d_in, const int* in_sizes, int n_in,
                              void* d_out, int out_size, void* d_ws, size_t ws_size,
                              hipStream_t stream) {
    (void)in_sizes; (void)n_in; (void)out_size; (void)ws_size;
    const float* x  = (const float*)d_in[0];
    const float* W1 = (const float*)d_in[1];
    const float* r1 = (const float*)d_in[2];
    const float* b1 = (const float*)d_in[3];
    const float* W2 = (const float*)d_in[4];
    const float* r2 = (const float*)d_in[5];
    const float* b2 = (const float*)d_in[6];
    const int* src = (const int*)d_in[7];
    const int* dst = (const int*)d_in[8];
    const int* et  = (const int*)d_in[9];
    float* out = (float*)d_out;

    char* w = (char*)d_ws;
    auto take = [&](size_t bytes) {
        char* p = w;
        w += (bytes + 255) & ~(size_t)255;
        return p;
    };
    int*    cnt    = (int*)   take((size_t)SEGS * 4);
    int*    cursor = (int*)   take((size_t)SEGS * 4);
    int*    bsum   = (int*)   take((size_t)SCAN_NB * 4);
    int*    esrc   = (int*)   take((size_t)EE * 4);
    __bf16* x_hi  = (__bf16*)take((size_t)NN * CIN * 2);
    __bf16* x_lo  = (__bf16*)take((size_t)NN * CIN * 2);
    __bf16* hh    = (__bf16*)take((size_t)NN * CHID * 2);
    __bf16* hl    = (__bf16*)take((size_t)NN * CHID * 2);
    __bf16* W1t_h = (__bf16*)take((size_t)RR * CIN * CHID * 2);
    __bf16* W1t_l = (__bf16*)take((size_t)RR * CIN * CHID * 2);
    __bf16* r1t_h = (__bf16*)take((size_t)CIN * CHID * 2);
    __bf16* r1t_l = (__bf16*)take((size_t)CIN * CHID * 2);
    __bf16* W2c_h = (__bf16*)take((size_t)COUT * K2 * 2);   // [512 cols][2304] catted rels+root
    __bf16* W2c_l = (__bf16*)take((size_t)COUT * K2 * 2);
    // arena reused across phases.
    // L1 phase: xW0 (51.2 MB) + xW1 (51.2 MB) + h_pre (51.2 MB).
    // L2 phase: G2 hi/lo (204.8 MB) — valid since h_pre is dead after finish1.
    char* arena = take((size_t)MHALF * K2S * 2 * 2);
    float*  xW0   = (float*)arena;
    float*  xW1   = (float*)(arena + (size_t)NN * CHID * 4);
    float*  h_pre = (float*)(arena + (size_t)NN * CHID * 8);
    __bf16* G2h   = (__bf16*)arena;                              // [25000][2048]
    __bf16* G2l   = (__bf16*)(arena + (size_t)MHALF * K2S * 2);

    hipMemsetAsync(cnt, 0, (size_t)SEGS * 4, stream);

    cvt_split<<<(NN * CIN / 4 + 255) / 256, 256, 0, stream>>>(x, x_hi, x_lo, NN * CIN / 4);
    // W1[r][512][256] -> W1t[r][256][512]
    wprep<<<dim3((CIN * CHID + 255) / 256, 1, RR), 256, 0, stream>>>(
        W1, W1t_h, W1t_l, CIN, CHID, CIN, 0, 0, CIN * CHID);
    wprep<<<dim3((CIN * CHID + 255) / 256, 1, 1), 256, 0, stream>>>(
        r1, r1t_h, r1t_l, CIN, CHID, CIN, 0, 0, 0);
    // W2[r][256][512] -> W2cat[512][r*256 + k];  root2 -> W2cat[512][2048 + k]
    wprep<<<dim3((CHID * COUT + 255) / 256, 1, RR), 256, 0, stream>>>(
        W2, W2c_h, W2c_l, CHID, COUT, K2, 0, CHID, 0);
    wprep<<<dim3((CHID * COUT + 255) / 256, 1, 1), 256, 0, stream>>>(
        r2, W2c_h, W2c_l, CHID, COUT, K2, K2S, 0, 0);

    // counting sort of edges by (rel,dst)
    count_edges<<<(EE + 255) / 256, 256, 0, stream>>>(et, dst, cnt);
    scan_partial<<<SCAN_NB, SCAN_BS, 0, stream>>>(cnt, bsum);
    scan_bsum<<<1, 512, 0, stream>>>(bsum);
    scan_final<<<SCAN_NB, SCAN_BS, 0, stream>>>(cnt, bsum, cursor);
    bucket_fill<<<(EE + 255) / 256, 256, 0, stream>>>(src, dst, et, cursor, esrc);

    const int MT1 = (NN + 255) / 256;      // 196 (NT=1)
    const int MT2 = (MHALF + 255) / 256;   // 98  (NT=2 -> 196 wg)

    // ---- layer 1: root-first, then per-relation-pair transform + gather-RMW ----
    gemm256<CIN, CIN, CIN, CIN, CHID, 3><<<MT1, 512, 0, stream>>>(
        x_hi, x_lo, x_hi, x_lo, r1t_h, r1t_l, h_pre, b1, NN);
    for (int rp = 0; rp < RR / 2; ++rp) {
        const int rel = rp * 2;
        gemm256<CIN, CIN, CIN, CIN, CHID, 0><<<MT1, 512, 0, stream>>>(
            x_hi, x_lo, x_hi, x_lo,
            W1t_h + (size_t)rel * CIN * CHID, W1t_l + (size_t)rel * CIN * CHID,
            xW0, nullptr, NN);
        gemm256<CIN, CIN, CIN, CIN, CHID, 0><<<MT1, 512, 0, stream>>>(
            x_hi, x_lo, x_hi, x_lo,
            W1t_h + (size_t)(rel + 1) * CIN * CHID, W1t_l + (size_t)(rel + 1) * CIN * CHID,
            xW1, nullptr, NN);
        gather_l1_pair<<<(NN + 3) / 4, 256, 0, stream>>>(xW0, xW1, esrc, cursor, cnt,
                                                         h_pre, rel);
    }
    finish1<<<(NN * CHID / 4 + 255) / 256, 256, 0, stream>>>(h_pre, hh, hl);

    // ---- layer 2: aggregate-then-transform, two M-halves, single K=2304 GEMM each ----
    for (int half = 0; half < 2; ++half) {
        gather_g2<<<(RR * MHALF + 3) / 4, 256, 0, stream>>>(hh, hl, esrc, cursor, cnt,
                                                            G2h, G2l, half);
        gemm256<K2, K2S, K2S, CHID, COUT, 3><<<MT2 * 2, 512, 0, stream>>>(
            G2h, G2l, hh + (size_t)half * MHALF * CHID, hl + (size_t)half * MHALF * CHID,
            W2c_h, W2c_l, out + (size_t)half * MHALF * COUT, b2, MHALF);
    }

    l2norm<<<(NN + 3) / 4, 256, 0, stream>>>(out);
}

// Round 8
// 1024.349 us; speedup vs baseline: 1.9205x; 1.9205x over previous
//
#include <hip/hip_runtime.h>
#include <hip/hip_bf16.h>
#include <stdint.h>

#define NN   50000
#define EE   800000
#define RR   8
#define CIN  512
#define CHID 256
#define COUT 512
#define SEGS (RR * NN)
#define MHALF 25000
#define K2   2304              // 8*CHID + CHID (relations + root)
#define K2S  2048              // split point: below = G2, above = h

typedef _Float16 f16;
typedef _Float16 f16x8 __attribute__((ext_vector_type(8)));
typedef _Float16 f16x4 __attribute__((ext_vector_type(4)));
typedef float    f32x4 __attribute__((ext_vector_type(4)));

constexpr int SCAN_BS = 256, SCAN_ITEMS = 4, SCAN_CHUNK = SCAN_BS * SCAN_ITEMS; // 1024
constexpr int SCAN_NB = (SEGS + SCAN_CHUNK - 1) / SCAN_CHUNK;                   // 391

__device__ __forceinline__ f32x4 mfma_f16(f16x8 a, f16x8 b, f32x4 c) {
    return __builtin_amdgcn_mfma_f32_16x16x32_f16(a, b, c, 0, 0, 0);
}

__device__ __forceinline__ void gload_lds16(const void* g, void* l) {
    __builtin_amdgcn_global_load_lds((const __attribute__((address_space(1))) void*)g,
                                     (__attribute__((address_space(3))) void*)l, 16, 0, 0);
}

// ---------------- prep: fp32 -> fp16 (8 elems/thread) ----------------
__global__ void cvt16(const float* __restrict__ in, f16* __restrict__ o, int n8) {
    int i = blockIdx.x * blockDim.x + threadIdx.x;
    if (i >= n8) return;
    f32x4 a = ((const f32x4*)in)[2 * i];
    f32x4 b = ((const f32x4*)in)[2 * i + 1];
    f16x8 v;
#pragma unroll
    for (int j = 0; j < 4; ++j) { v[j] = (f16)a[j]; v[4 + j] = (f16)b[j]; }
    ((f16x8*)o)[i] = v;
}

// transpose weights into B^T layout: dst[rel*relstride + col*Ktot + koffbase + rel*koffstride + k]
__global__ void wprep16(const float* __restrict__ W, f16* __restrict__ o,
                        int K0, int NC, int Ktot, int koffbase, int koffstride,
                        int relstride) {
    int r = blockIdx.z;
    int idx = blockIdx.x * blockDim.x + threadIdx.x;
    if (idx >= K0 * NC) return;
    int k = idx / NC, c = idx % NC;
    float v = W[(size_t)r * K0 * NC + idx];
    o[(size_t)r * relstride + (size_t)c * Ktot + koffbase + r * koffstride + k] = (f16)v;
}

// ---------------- per-(rel,dst) edge counts ----------------
__global__ void count_edges(const int* __restrict__ et, const int* __restrict__ dst,
                            int* __restrict__ cnt) {
    int e = blockIdx.x * blockDim.x + threadIdx.x;
    if (e < EE) atomicAdd(&cnt[et[e] * NN + dst[e]], 1);
}

// ---------------- exclusive scan of cnt[SEGS] -> cursor (3-pass) ----------------
__global__ void scan_partial(const int* __restrict__ cnt, int* __restrict__ bsum) {
    __shared__ int lds[SCAN_BS];
    const int b = blockIdx.x, t = threadIdx.x;
    const int base = b * SCAN_CHUNK + t * SCAN_ITEMS;
    int s = 0;
#pragma unroll
    for (int j = 0; j < SCAN_ITEMS; ++j) {
        int i = base + j;
        if (i < SEGS) s += cnt[i];
    }
    lds[t] = s;
    __syncthreads();
    for (int off = SCAN_BS / 2; off > 0; off >>= 1) {
        if (t < off) lds[t] += lds[t + off];
        __syncthreads();
    }
    if (t == 0) bsum[b] = lds[0];
}

__global__ void scan_bsum(int* __restrict__ bsum) {
    __shared__ int lds[512];
    const int t = threadIdx.x;
    const int v = (t < SCAN_NB) ? bsum[t] : 0;
    lds[t] = v;
    __syncthreads();
    for (int off = 1; off < 512; off <<= 1) {
        int x = (t >= off) ? lds[t - off] : 0;
        __syncthreads();
        lds[t] += x;
        __syncthreads();
    }
    if (t < SCAN_NB) bsum[t] = lds[t] - v;   // exclusive
}

__global__ void scan_final(const int* __restrict__ cnt, const int* __restrict__ bsum,
                           int* __restrict__ cursor) {
    __shared__ int lds[SCAN_BS];
    const int b = blockIdx.x, t = threadIdx.x;
    const int base = b * SCAN_CHUNK + t * SCAN_ITEMS;
    int v[SCAN_ITEMS];
    int s = 0;
#pragma unroll
    for (int j = 0; j < SCAN_ITEMS; ++j) {
        int i = base + j;
        v[j] = (i < SEGS) ? cnt[i] : 0;
        s += v[j];
    }
    lds[t] = s;
    __syncthreads();
    for (int off = 1; off < SCAN_BS; off <<= 1) {
        int x = (t >= off) ? lds[t - off] : 0;
        __syncthreads();
        lds[t] += x;
        __syncthreads();
    }
    int run = lds[t] - s + bsum[b];
#pragma unroll
    for (int j = 0; j < SCAN_ITEMS; ++j) {
        int i = base + j;
        if (i < SEGS) cursor[i] = run;
        run += v[j];
    }
}

// ---------------- bucket fill: esrc sorted by (rel,dst) segment ----------------
// after this pass, cursor[s] == segment END offset (begin = end - cnt[s])
__global__ void bucket_fill(const int* __restrict__ src, const int* __restrict__ dst,
                            const int* __restrict__ et, int* __restrict__ cursor,
                            int* __restrict__ esrc) {
    int e = blockIdx.x * blockDim.x + threadIdx.x;
    if (e < EE) {
        int s = et[e] * NN + dst[e];
        int pos = atomicAdd(&cursor[s], 1);
        esrc[pos] = src[e];
    }
}

// ---------------- fp16 MFMA GEMM, 128x128 tile, BK=64, dual A-source ----------------
// C[M,NC] = A[M,K] @ B^T[NC,K]^T with A = [A1 (k<K1) | A2 (k>=K1)], all fp16, 1-term.
// Proven round-3/4 2-phase structure (4 blocks/CU, plain __syncthreads, compiler waitcnt).
// LDS = sA[128][64] | sB[128][64] fp16 = 32 KB. Chunk-XOR swizzle (chunk' = chunk ^ (row&7))
// applied via pre-swizzled GLOBAL source (linear gload_lds dest, rule #21) + swizzled read.
// EPI 0: O16[o] = (f16)v (xW);  EPI 3: C[o] = v + bias[col] (h_pre root / final out fp32).
template <int K, int K1, int SA1, int SA2, int NC, int EPI>
__global__ __launch_bounds__(256, 4) void gemm16(
    const f16* __restrict__ A1, const f16* __restrict__ A2,
    const f16* __restrict__ B, float* __restrict__ C,
    const float* __restrict__ bias, f16* __restrict__ O16, int M) {
    __shared__ f16 lds[16384];             // 32 KB
    f16* sA = lds;
    f16* sB = lds + 8192;
    constexpr int NT = NC / 128;

    // bijective XCD-aware swizzle (m204)
    const int nwg = gridDim.x;
    const int orig = blockIdx.x;
    const int q8 = nwg >> 3, r8 = nwg & 7;
    const int xcd = orig & 7, lin = orig >> 3;
    const int wg = (xcd < r8 ? xcd * (q8 + 1) : r8 * (q8 + 1) + (xcd - r8) * q8) + lin;
    const int mtile = wg / NT, ntile = wg % NT;
    const int row0 = mtile * 128, col0 = ntile * 128;

    const int t = threadIdx.x;
    const int lane = t & 63;
    const int wid = t >> 6;
    const int wm = wid >> 1, wn = wid & 1;
    const int fr = lane & 15;

    f32x4 acc[4][4] = {};

    for (int ks = 0; ks < K / 64; ++ks) {
        const int k0 = ks * 64;
        const bool useA2 = (K1 < K) && (k0 >= K1);
        const f16* Ab = useA2 ? A2 : A1;
        const int astr = useA2 ? SA2 : SA1;
        const int ak0 = useA2 ? k0 - K1 : k0;
#pragma unroll
        for (int i = 0; i < 4; ++i) {
            const int flat = i * 256 + t;      // 1024 16B-chunks per matrix
            const int rr = flat >> 3;
            const int scol = ((flat & 7) ^ (rr & 7)) * 8;  // inverse-swizzled source chunk
            int ra = row0 + rr;
            ra = ra < M ? ra : M - 1;          // clamp tail rows (masked at store)
            gload_lds16(Ab + (size_t)ra * astr + ak0 + scol, sA + flat * 8);
            gload_lds16(B + (size_t)(col0 + rr) * K + k0 + scol, sB + flat * 8);
        }
        __syncthreads();
#pragma unroll
        for (int kk = 0; kk < 2; ++kk) {
            const int ch = ((kk * 4 + (lane >> 4)) ^ (fr & 7)) * 8;  // swizzled read chunk
            f16x8 fa[4], fb[4];
#pragma unroll
            for (int m = 0; m < 4; ++m)
                fa[m] = *(const f16x8*)(sA + (wm * 64 + m * 16 + fr) * 64 + ch);
#pragma unroll
            for (int n = 0; n < 4; ++n)
                fb[n] = *(const f16x8*)(sB + (wn * 64 + n * 16 + fr) * 64 + ch);
#pragma unroll
            for (int m = 0; m < 4; ++m)
#pragma unroll
                for (int n = 0; n < 4; ++n)
                    acc[m][n] = mfma_f16(fa[m], fb[n], acc[m][n]);
        }
        __syncthreads();
    }

#pragma unroll
    for (int m = 0; m < 4; ++m)
#pragma unroll
        for (int n = 0; n < 4; ++n)
#pragma unroll
            for (int qq = 0; qq < 4; ++qq) {
                int row = row0 + wm * 64 + m * 16 + (lane >> 4) * 4 + qq;
                int col = col0 + wn * 64 + n * 16 + fr;
                if (row < M) {
                    size_t o = (size_t)row * NC + col;
                    float v = acc[m][n][qq];
                    if (EPI == 0) O16[o] = (f16)v;
                    else C[o] = v + bias[col];
                }
            }
}

// ---------------- L1 gather (2 relations per pass): h_pre[d] += sum of both rel-means ----------------
// xW is fp16 [N][256]; lane covers 4 cols (8B read, f32x4 RMW)
__global__ void gather_l1_pair(const f16* __restrict__ xW0, const f16* __restrict__ xW1,
                               const int* __restrict__ esrc, const int* __restrict__ cursor,
                               const int* __restrict__ cnt, float* __restrict__ h_pre,
                               int rel0) {
    const int d = blockIdx.x * 4 + (threadIdx.x >> 6);
    if (d >= NN) return;
    const int lane = threadIdx.x & 63;
    const int s0 = rel0 * NN + d;
    const int s1 = s0 + NN;
    const int n0 = cnt[s0], n1 = cnt[s1];
    if ((n0 | n1) == 0) return;
    f32x4 v = {};
    if (n0 > 0) {
        const int end = cursor[s0];
        f32x4 acc = {};
        for (int i = end - n0; i < end; ++i) {
            f16x4 a = *(const f16x4*)(xW0 + (size_t)esrc[i] * CHID + lane * 4);
#pragma unroll
            for (int j = 0; j < 4; ++j) acc[j] += (float)a[j];
        }
        v += acc * (1.0f / (float)n0);
    }
    if (n1 > 0) {
        const int end = cursor[s1];
        f32x4 acc = {};
        for (int i = end - n1; i < end; ++i) {
            f16x4 a = *(const f16x4*)(xW1 + (size_t)esrc[i] * CHID + lane * 4);
#pragma unroll
            for (int j = 0; j < 4; ++j) acc[j] += (float)a[j];
        }
        v += acc * (1.0f / (float)n1);
    }
    ((f32x4*)(h_pre + (size_t)d * CHID))[lane] += v;
}

// ---------------- finish1: h = relu(h_pre) -> fp16 ----------------
__global__ void finish1(const float* __restrict__ h_pre, f16* __restrict__ hh) {
    int i = blockIdx.x * blockDim.x + threadIdx.x;
    if (i >= NN * CHID / 4) return;
    f32x4 v = ((const f32x4*)h_pre)[i];
    f16x4 a;
#pragma unroll
    for (int j = 0; j < 4; ++j) a[j] = (f16)fmaxf(v[j], 0.0f);
    ((f16x4*)hh)[i] = a;
}

// ---------------- L2 gather-aggregate: G2[dloc, rel*256+c] = mean_{seg(rel,d)} h[src,c] ----------------
// plain stores (no nontemporal): G2-half fp16 = 102 MB, keep L3-resident for the GEMM
__global__ void gather_g2(const f16* __restrict__ hh, const int* __restrict__ esrc,
                          const int* __restrict__ cursor, const int* __restrict__ cnt,
                          f16* __restrict__ G2h, int half) {
    const int sidx = blockIdx.x * 4 + (threadIdx.x >> 6);
    if (sidx >= RR * MHALF) return;
    const int lane = threadIdx.x & 63;
    const int rel = sidx / MHALF;
    const int dloc = sidx % MHALF;
    const int d = half * MHALF + dloc;
    const int s = rel * NN + d;
    const int n = cnt[s];
    f32x4 v = {};
    if (n > 0) {
        const int end = cursor[s];
        for (int i = end - n; i < end; ++i) {
            f16x4 a = *(const f16x4*)(hh + (size_t)esrc[i] * CHID + lane * 4);
#pragma unroll
            for (int j = 0; j < 4; ++j) v[j] += (float)a[j];
        }
        const float inv = 1.0f / (float)n;
#pragma unroll
        for (int j = 0; j < 4; ++j) v[j] *= inv;
    }
    f16x4 o;
#pragma unroll
    for (int j = 0; j < 4; ++j) o[j] = (f16)v[j];
    *(f16x4*)(G2h + (size_t)dloc * K2S + rel * CHID + lane * 4) = o;
}

// ---------------- row-wise L2 normalize (one wave per 512-col row) ----------------
__global__ void l2norm(float* __restrict__ out) {
    int row = blockIdx.x * 4 + (threadIdx.x >> 6);
    int lane = threadIdx.x & 63;
    if (row >= NN) return;
    float* p = out + (size_t)row * COUT;
    f32x4 a = ((const f32x4*)p)[lane];
    f32x4 b = ((const f32x4*)p)[lane + 64];
    float ss = a[0] * a[0] + a[1] * a[1] + a[2] * a[2] + a[3] * a[3] +
               b[0] * b[0] + b[1] * b[1] + b[2] * b[2] + b[3] * b[3];
#pragma unroll
    for (int m = 32; m >= 1; m >>= 1) ss += __shfl_xor(ss, m, 64);
    const float s = 1.0f / fmaxf(sqrtf(ss), 1e-12f);
#pragma unroll
    for (int j = 0; j < 4; ++j) { a[j] *= s; b[j] *= s; }
    ((f32x4*)p)[lane] = a;
    ((f32x4*)p)[lane + 64] = b;
}

extern "C" void kernel_launch(void* const* d_in, const int* in_sizes, int n_in,
                              void* d_out, int out_size, void* d_ws, size_t ws_size,
                              hipStream_t stream) {
    (void)in_sizes; (void)n_in; (void)out_size; (void)ws_size;
    const float* x  = (const float*)d_in[0];
    const float* W1 = (const float*)d_in[1];
    const float* r1 = (const float*)d_in[2];
    const float* b1 = (const float*)d_in[3];
    const float* W2 = (const float*)d_in[4];
    const float* r2 = (const float*)d_in[5];
    const float* b2 = (const float*)d_in[6];
    const int* src = (const int*)d_in[7];
    const int* dst = (const int*)d_in[8];
    const int* et  = (const int*)d_in[9];
    float* out = (float*)d_out;

    char* w = (char*)d_ws;
    auto take = [&](size_t bytes) {
        char* p = w;
        w += (bytes + 255) & ~(size_t)255;
        return p;
    };
    int* cnt    = (int*)take((size_t)SEGS * 4);
    int* cursor = (int*)take((size_t)SEGS * 4);
    int* bsum   = (int*)take((size_t)SCAN_NB * 4);
    int* esrc   = (int*)take((size_t)EE * 4);
    f16* x16  = (f16*)take((size_t)NN * CIN * 2);
    f16* hh   = (f16*)take((size_t)NN * CHID * 2);
    f16* W1t  = (f16*)take((size_t)RR * CIN * CHID * 2);
    f16* r1t  = (f16*)take((size_t)CIN * CHID * 2);
    f16* W2c  = (f16*)take((size_t)COUT * K2 * 2);   // [512 cols][2304] catted rels+root
    // arena reused: L1 phase xW0(25.6) + xW1(25.6) + h_pre(51.2); L2 phase G2h(102.4 MB)
    char* arena = take((size_t)MHALF * K2S * 2);
    f16*   xW0   = (f16*)arena;
    f16*   xW1   = (f16*)(arena + (size_t)NN * CHID * 2);
    float* h_pre = (float*)(arena + (size_t)NN * CHID * 4);
    f16*   G2h   = (f16*)arena;                      // [25000][2048] fp16

    hipMemsetAsync(cnt, 0, (size_t)SEGS * 4, stream);

    cvt16<<<(NN * CIN / 8 + 255) / 256, 256, 0, stream>>>(x, x16, NN * CIN / 8);
    // W1[r][512][256] -> W1t[r][256 cols][512]
    wprep16<<<dim3((CIN * CHID + 255) / 256, 1, RR), 256, 0, stream>>>(
        W1, W1t, CIN, CHID, CIN, 0, 0, CIN * CHID);
    wprep16<<<dim3((CIN * CHID + 255) / 256, 1, 1), 256, 0, stream>>>(
        r1, r1t, CIN, CHID, CIN, 0, 0, 0);
    // W2[r][256][512] -> W2c[512 cols][r*256 + k]; root2 -> W2c[512][2048 + k]
    wprep16<<<dim3((CHID * COUT + 255) / 256, 1, RR), 256, 0, stream>>>(
        W2, W2c, CHID, COUT, K2, 0, CHID, 0);
    wprep16<<<dim3((CHID * COUT + 255) / 256, 1, 1), 256, 0, stream>>>(
        r2, W2c, CHID, COUT, K2, K2S, 0, 0);

    // counting sort of edges by (rel,dst)
    count_edges<<<(EE + 255) / 256, 256, 0, stream>>>(et, dst, cnt);
    scan_partial<<<SCAN_NB, SCAN_BS, 0, stream>>>(cnt, bsum);
    scan_bsum<<<1, 512, 0, stream>>>(bsum);
    scan_final<<<SCAN_NB, SCAN_BS, 0, stream>>>(cnt, bsum, cursor);
    bucket_fill<<<(EE + 255) / 256, 256, 0, stream>>>(src, dst, et, cursor, esrc);

    const int MT1 = (NN + 127) / 128;     // 391
    const int MT2 = (MHALF + 127) / 128;  // 196

    // ---- layer 1: root-first (h_pre = x@root1 + b1), then rel-pair transform + gather-RMW ----
    gemm16<CIN, CIN, CIN, CIN, CHID, 3><<<MT1 * 2, 256, 0, stream>>>(
        x16, x16, r1t, h_pre, b1, nullptr, NN);
    for (int rp = 0; rp < RR / 2; ++rp) {
        const int rel = rp * 2;
        gemm16<CIN, CIN, CIN, CIN, CHID, 0><<<MT1 * 2, 256, 0, stream>>>(
            x16, x16, W1t + (size_t)rel * CIN * CHID, nullptr, nullptr, xW0, NN);
        gemm16<CIN, CIN, CIN, CIN, CHID, 0><<<MT1 * 2, 256, 0, stream>>>(
            x16, x16, W1t + (size_t)(rel + 1) * CIN * CHID, nullptr, nullptr, xW1, NN);
        gather_l1_pair<<<(NN + 3) / 4, 256, 0, stream>>>(xW0, xW1, esrc, cursor, cnt,
                                                         h_pre, rel);
    }
    finish1<<<(NN * CHID / 4 + 255) / 256, 256, 0, stream>>>(h_pre, hh);

    // ---- layer 2: aggregate-then-transform, two M-halves, single K=2304 GEMM each ----
    for (int half = 0; half < 2; ++half) {
        gather_g2<<<(RR * MHALF + 3) / 4, 256, 0, stream>>>(hh, esrc, cursor, cnt,
                                                            G2h, half);
        gemm16<K2, K2S, K2S, CHID, COUT, 3><<<MT2 * 4, 256, 0, stream>>>(
            G2h, hh + (size_t)half * MHALF * CHID, W2c,
            out + (size_t)half * MHALF * COUT, b2, nullptr, MHALF);
    }

    l2norm<<<(NN + 3) / 4, 256, 0, stream>>>(out);
}

// Round 9
// 971.394 us; speedup vs baseline: 2.0252x; 1.0545x over previous
//
#include <hip/hip_runtime.h>
#include <hip/hip_bf16.h>
#include <stdint.h>

#define NN   50000
#define EE   800000
#define RR   8
#define CIN  512
#define CHID 256
#define COUT 512
#define SEGS (RR * NN)
#define K2   2304              // 8*CHID + CHID (relations + root), layer-2 K
#define K2S  2048              // split: k<2048 = G2, k>=2048 = h
#define N1   2304              // layer-1 fused output cols: 8*CHID rels + CHID root

typedef _Float16 f16;
typedef _Float16 f16x8 __attribute__((ext_vector_type(8)));
typedef _Float16 f16x4 __attribute__((ext_vector_type(4)));
typedef float    f32x4 __attribute__((ext_vector_type(4)));

constexpr int SCAN_BS = 256, SCAN_ITEMS = 4, SCAN_CHUNK = SCAN_BS * SCAN_ITEMS; // 1024
constexpr int SCAN_NB = (SEGS + SCAN_CHUNK - 1) / SCAN_CHUNK;                   // 391

__device__ __forceinline__ f32x4 mfma_f16(f16x8 a, f16x8 b, f32x4 c) {
    return __builtin_amdgcn_mfma_f32_16x16x32_f16(a, b, c, 0, 0, 0);
}

__device__ __forceinline__ void gload_lds16(const void* g, void* l) {
    __builtin_amdgcn_global_load_lds((const __attribute__((address_space(1))) void*)g,
                                     (__attribute__((address_space(3))) void*)l, 16, 0, 0);
}

// ---------------- prep: fp32 -> fp16 (8 elems/thread) ----------------
__global__ void cvt16(const float* __restrict__ in, f16* __restrict__ o, int n8) {
    int i = blockIdx.x * blockDim.x + threadIdx.x;
    if (i >= n8) return;
    f32x4 a = ((const f32x4*)in)[2 * i];
    f32x4 b = ((const f32x4*)in)[2 * i + 1];
    f16x8 v;
#pragma unroll
    for (int j = 0; j < 4; ++j) { v[j] = (f16)a[j]; v[4 + j] = (f16)b[j]; }
    ((f16x8*)o)[i] = v;
}

// transpose weights into B^T layout: dst[r*relstride + c*Ktot + koffbase + r*koffstride + k]
__global__ void wprep16(const float* __restrict__ W, f16* __restrict__ o,
                        int K0, int NC, int Ktot, int koffbase, int koffstride,
                        int relstride) {
    int r = blockIdx.z;
    int idx = blockIdx.x * blockDim.x + threadIdx.x;
    if (idx >= K0 * NC) return;
    int k = idx / NC, c = idx % NC;
    float v = W[(size_t)r * K0 * NC + idx];
    o[(size_t)r * relstride + (size_t)c * Ktot + koffbase + r * koffstride + k] = (f16)v;
}

// ---------------- per-(rel,dst) edge counts ----------------
__global__ void count_edges(const int* __restrict__ et, const int* __restrict__ dst,
                            int* __restrict__ cnt) {
    int e = blockIdx.x * blockDim.x + threadIdx.x;
    if (e < EE) atomicAdd(&cnt[et[e] * NN + dst[e]], 1);
}

// ---------------- exclusive scan of cnt[SEGS] -> cursor (3-pass) ----------------
__global__ void scan_partial(const int* __restrict__ cnt, int* __restrict__ bsum) {
    __shared__ int lds[SCAN_BS];
    const int b = blockIdx.x, t = threadIdx.x;
    const int base = b * SCAN_CHUNK + t * SCAN_ITEMS;
    int s = 0;
#pragma unroll
    for (int j = 0; j < SCAN_ITEMS; ++j) {
        int i = base + j;
        if (i < SEGS) s += cnt[i];
    }
    lds[t] = s;
    __syncthreads();
    for (int off = SCAN_BS / 2; off > 0; off >>= 1) {
        if (t < off) lds[t] += lds[t + off];
        __syncthreads();
    }
    if (t == 0) bsum[b] = lds[0];
}

__global__ void scan_bsum(int* __restrict__ bsum) {
    __shared__ int lds[512];
    const int t = threadIdx.x;
    const int v = (t < SCAN_NB) ? bsum[t] : 0;
    lds[t] = v;
    __syncthreads();
    for (int off = 1; off < 512; off <<= 1) {
        int x = (t >= off) ? lds[t - off] : 0;
        __syncthreads();
        lds[t] += x;
        __syncthreads();
    }
    if (t < SCAN_NB) bsum[t] = lds[t] - v;   // exclusive
}

__global__ void scan_final(const int* __restrict__ cnt, const int* __restrict__ bsum,
                           int* __restrict__ cursor) {
    __shared__ int lds[SCAN_BS];
    const int b = blockIdx.x, t = threadIdx.x;
    const int base = b * SCAN_CHUNK + t * SCAN_ITEMS;
    int v[SCAN_ITEMS];
    int s = 0;
#pragma unroll
    for (int j = 0; j < SCAN_ITEMS; ++j) {
        int i = base + j;
        v[j] = (i < SEGS) ? cnt[i] : 0;
        s += v[j];
    }
    lds[t] = s;
    __syncthreads();
    for (int off = 1; off < SCAN_BS; off <<= 1) {
        int x = (t >= off) ? lds[t - off] : 0;
        __syncthreads();
        lds[t] += x;
        __syncthreads();
    }
    int run = lds[t] - s + bsum[b];
#pragma unroll
    for (int j = 0; j < SCAN_ITEMS; ++j) {
        int i = base + j;
        if (i < SEGS) cursor[i] = run;
        run += v[j];
    }
}

// ---------------- bucket fill: esrc sorted by (rel,dst) segment ----------------
// after this pass, cursor[s] == segment END offset (begin = end - cnt[s])
__global__ void bucket_fill(const int* __restrict__ src, const int* __restrict__ dst,
                            const int* __restrict__ et, int* __restrict__ cursor,
                            int* __restrict__ esrc) {
    int e = blockIdx.x * blockDim.x + threadIdx.x;
    if (e < EE) {
        int s = et[e] * NN + dst[e];
        int pos = atomicAdd(&cursor[s], 1);
        esrc[pos] = src[e];
    }
}

// ---------------- fp16 MFMA GEMM, 128x128 tile, BK=64, dual A-source ----------------
// C[M,NC] = A[M,K] @ B^T[NC,K]^T with A = [A1 (k<K1) | A2 (k>=K1)], all fp16, 1-term.
// Proven 2-phase structure (4 blocks/CU, plain __syncthreads, compiler waitcnt).
// LDS = sA[128][64] | sB[128][64] fp16 = 32 KB. Chunk-XOR swizzle (chunk' = chunk ^ (row&7))
// via pre-swizzled GLOBAL source (linear gload_lds dest, rule #21) + swizzled read.
// EPI 3: C[row*NC + col] = v + bias[col]                     (layer-2 final out, fp32)
// EPI 4: col<2048 -> O16[row*2048+col] = (f16)v (xWall);     (fused layer-1)
//        col>=2048 -> C[row*256 + col-2048] = v + bias[..]   (h_pre root+bias, fp32)
template <int K, int K1, int SA1, int SA2, int NC, int EPI>
__global__ __launch_bounds__(256, 4) void gemm16(
    const f16* __restrict__ A1, const f16* __restrict__ A2,
    const f16* __restrict__ B, float* __restrict__ C,
    const float* __restrict__ bias, f16* __restrict__ O16, int M) {
    __shared__ f16 lds[16384];             // 32 KB
    f16* sA = lds;
    f16* sB = lds + 8192;
    constexpr int NT = NC / 128;

    // bijective XCD-aware swizzle (m204)
    const int nwg = gridDim.x;
    const int orig = blockIdx.x;
    const int q8 = nwg >> 3, r8 = nwg & 7;
    const int xcd = orig & 7, lin = orig >> 3;
    const int wg = (xcd < r8 ? xcd * (q8 + 1) : r8 * (q8 + 1) + (xcd - r8) * q8) + lin;
    const int mtile = wg / NT, ntile = wg % NT;
    const int row0 = mtile * 128, col0 = ntile * 128;

    const int t = threadIdx.x;
    const int lane = t & 63;
    const int wid = t >> 6;
    const int wm = wid >> 1, wn = wid & 1;
    const int fr = lane & 15;

    f32x4 acc[4][4] = {};

    for (int ks = 0; ks < K / 64; ++ks) {
        const int k0 = ks * 64;
        const bool useA2 = (K1 < K) && (k0 >= K1);
        const f16* Ab = useA2 ? A2 : A1;
        const int astr = useA2 ? SA2 : SA1;
        const int ak0 = useA2 ? k0 - K1 : k0;
#pragma unroll
        for (int i = 0; i < 4; ++i) {
            const int flat = i * 256 + t;      // 1024 16B-chunks per matrix
            const int rr = flat >> 3;
            const int scol = ((flat & 7) ^ (rr & 7)) * 8;  // inverse-swizzled source chunk
            int ra = row0 + rr;
            ra = ra < M ? ra : M - 1;          // clamp tail rows (masked at store)
            gload_lds16(Ab + (size_t)ra * astr + ak0 + scol, sA + flat * 8);
            gload_lds16(B + (size_t)(col0 + rr) * K + k0 + scol, sB + flat * 8);
        }
        __syncthreads();
#pragma unroll
        for (int kk = 0; kk < 2; ++kk) {
            const int ch = ((kk * 4 + (lane >> 4)) ^ (fr & 7)) * 8;  // swizzled read chunk
            f16x8 fa[4], fb[4];
#pragma unroll
            for (int m = 0; m < 4; ++m)
                fa[m] = *(const f16x8*)(sA + (wm * 64 + m * 16 + fr) * 64 + ch);
#pragma unroll
            for (int n = 0; n < 4; ++n)
                fb[n] = *(const f16x8*)(sB + (wn * 64 + n * 16 + fr) * 64 + ch);
#pragma unroll
            for (int m = 0; m < 4; ++m)
#pragma unroll
                for (int n = 0; n < 4; ++n)
                    acc[m][n] = mfma_f16(fa[m], fb[n], acc[m][n]);
        }
        __syncthreads();
    }

#pragma unroll
    for (int m = 0; m < 4; ++m)
#pragma unroll
        for (int n = 0; n < 4; ++n)
#pragma unroll
            for (int qq = 0; qq < 4; ++qq) {
                int row = row0 + wm * 64 + m * 16 + (lane >> 4) * 4 + qq;
                int col = col0 + wn * 64 + n * 16 + fr;
                if (row < M) {
                    float v = acc[m][n][qq];
                    if (EPI == 3) {
                        C[(size_t)row * NC + col] = v + bias[col];
                    } else {                       // EPI 4 (block-uniform branch)
                        if (col < K2S) O16[(size_t)row * K2S + col] = (f16)v;
                        else C[(size_t)row * CHID + (col - K2S)] = v + bias[col - K2S];
                    }
                }
            }
}

// ---------------- fused L1 gather: hh[d] = relu(h_pre[d] + sum_rel mean xWall[src][rel]) ----------------
// one wave per dst; single h_pre read, single hh write; kills finish1 + multi-pass RMW
__global__ void gather_l1(const f16* __restrict__ xWall, const int* __restrict__ esrc,
                          const int* __restrict__ cursor, const int* __restrict__ cnt,
                          const float* __restrict__ h_pre, f16* __restrict__ hh) {
    const int d = blockIdx.x * 4 + (threadIdx.x >> 6);
    if (d >= NN) return;
    const int lane = threadIdx.x & 63;
    f32x4 v = ((const f32x4*)(h_pre + (size_t)d * CHID))[lane];
#pragma unroll
    for (int rel = 0; rel < RR; ++rel) {
        const int s = rel * NN + d;
        const int n = cnt[s];
        if (n == 0) continue;
        const int end = cursor[s];
        f32x4 acc = {};
        for (int i = end - n; i < end; ++i) {
            f16x4 a = *(const f16x4*)(xWall + (size_t)esrc[i] * K2S + rel * CHID + lane * 4);
#pragma unroll
            for (int j = 0; j < 4; ++j) acc[j] += (float)a[j];
        }
        v += acc * (1.0f / (float)n);
    }
    f16x4 o;
#pragma unroll
    for (int j = 0; j < 4; ++j) o[j] = (f16)fmaxf(v[j], 0.0f);
    *(f16x4*)(hh + (size_t)d * CHID + lane * 4) = o;
}

// ---------------- L2 gather-aggregate (full N): G2[d, rel*256+c] = mean_{seg(rel,d)} h[src,c] ----------------
// one wave per (rel,dst) segment; exclusive output slot -> no RMW, no atomics
__global__ void gather_g2(const f16* __restrict__ hh, const int* __restrict__ esrc,
                          const int* __restrict__ cursor, const int* __restrict__ cnt,
                          f16* __restrict__ G2) {
    const int sidx = blockIdx.x * 4 + (threadIdx.x >> 6);
    if (sidx >= SEGS) return;
    const int lane = threadIdx.x & 63;
    const int rel = sidx / NN;
    const int d = sidx % NN;
    const int n = cnt[sidx];
    f32x4 v = {};
    if (n > 0) {
        const int end = cursor[sidx];
        for (int i = end - n; i < end; ++i) {
            f16x4 a = *(const f16x4*)(hh + (size_t)esrc[i] * CHID + lane * 4);
#pragma unroll
            for (int j = 0; j < 4; ++j) v[j] += (float)a[j];
        }
        const float inv = 1.0f / (float)n;
#pragma unroll
        for (int j = 0; j < 4; ++j) v[j] *= inv;
    }
    f16x4 o;
#pragma unroll
    for (int j = 0; j < 4; ++j) o[j] = (f16)v[j];
    *(f16x4*)(G2 + (size_t)d * K2S + rel * CHID + lane * 4) = o;
}

// ---------------- row-wise L2 normalize (one wave per 512-col row) ----------------
__global__ void l2norm(float* __restrict__ out) {
    int row = blockIdx.x * 4 + (threadIdx.x >> 6);
    int lane = threadIdx.x & 63;
    if (row >= NN) return;
    float* p = out + (size_t)row * COUT;
    f32x4 a = ((const f32x4*)p)[lane];
    f32x4 b = ((const f32x4*)p)[lane + 64];
    float ss = a[0] * a[0] + a[1] * a[1] + a[2] * a[2] + a[3] * a[3] +
               b[0] * b[0] + b[1] * b[1] + b[2] * b[2] + b[3] * b[3];
#pragma unroll
    for (int m = 32; m >= 1; m >>= 1) ss += __shfl_xor(ss, m, 64);
    const float s = 1.0f / fmaxf(sqrtf(ss), 1e-12f);
#pragma unroll
    for (int j = 0; j < 4; ++j) { a[j] *= s; b[j] *= s; }
    ((f32x4*)p)[lane] = a;
    ((f32x4*)p)[lane + 64] = b;
}

extern "C" void kernel_launch(void* const* d_in, const int* in_sizes, int n_in,
                              void* d_out, int out_size, void* d_ws, size_t ws_size,
                              hipStream_t stream) {
    (void)in_sizes; (void)n_in; (void)out_size; (void)ws_size;
    const float* x  = (const float*)d_in[0];
    const float* W1 = (const float*)d_in[1];
    const float* r1 = (const float*)d_in[2];
    const float* b1 = (const float*)d_in[3];
    const float* W2 = (const float*)d_in[4];
    const float* r2 = (const float*)d_in[5];
    const float* b2 = (const float*)d_in[6];
    const int* src = (const int*)d_in[7];
    const int* dst = (const int*)d_in[8];
    const int* et  = (const int*)d_in[9];
    float* out = (float*)d_out;

    char* w = (char*)d_ws;
    auto take = [&](size_t bytes) {
        char* p = w;
        w += (bytes + 255) & ~(size_t)255;
        return p;
    };
    int* cnt    = (int*)take((size_t)SEGS * 4);
    int* cursor = (int*)take((size_t)SEGS * 4);
    int* bsum   = (int*)take((size_t)SCAN_NB * 4);
    int* esrc   = (int*)take((size_t)EE * 4);
    f16*   x16   = (f16*)take((size_t)NN * CIN * 2);      // 51.2 MB
    f16*   hh    = (f16*)take((size_t)NN * CHID * 2);     // 25.6 MB
    float* h_pre = (float*)take((size_t)NN * CHID * 4);   // 51.2 MB
    f16*   W1c   = (f16*)take((size_t)N1 * CIN * 2);      // [2304 cols][512]  2.36 MB
    f16*   W2c   = (f16*)take((size_t)COUT * K2 * 2);     // [512 cols][2304]  2.36 MB
    // arena: xWall [50000][2048] fp16 (L1 phase) aliased with G2 [50000][2048] (L2 phase)
    char* arena = take((size_t)NN * K2S * 2);             // 204.8 MB
    f16* xWall = (f16*)arena;
    f16* G2    = (f16*)arena;

    hipMemsetAsync(cnt, 0, (size_t)SEGS * 4, stream);

    cvt16<<<(NN * CIN / 8 + 255) / 256, 256, 0, stream>>>(x, x16, NN * CIN / 8);
    // W1[r][512][256] -> W1c col (rel*256+c), layout [col][512]: off = r*131072 + c*512 + k
    wprep16<<<dim3((CIN * CHID + 255) / 256, 1, RR), 256, 0, stream>>>(
        W1, W1c, CIN, CHID, CIN, 0, 0, CHID * CIN);
    // root1 -> W1c cols 2048..2303: off = c*512 + 2048*512 + k
    wprep16<<<dim3((CIN * CHID + 255) / 256, 1, 1), 256, 0, stream>>>(
        r1, W1c, CIN, CHID, CIN, K2S * CIN, 0, 0);
    // W2[r][256][512] -> W2c[512 cols][2304]: rel blocks along k; root at k 2048..2303
    wprep16<<<dim3((CHID * COUT + 255) / 256, 1, RR), 256, 0, stream>>>(
        W2, W2c, CHID, COUT, K2, 0, CHID, 0);
    wprep16<<<dim3((CHID * COUT + 255) / 256, 1, 1), 256, 0, stream>>>(
        r2, W2c, CHID, COUT, K2, K2S, 0, 0);

    // counting sort of edges by (rel,dst)
    count_edges<<<(EE + 255) / 256, 256, 0, stream>>>(et, dst, cnt);
    scan_partial<<<SCAN_NB, SCAN_BS, 0, stream>>>(cnt, bsum);
    scan_bsum<<<1, 512, 0, stream>>>(bsum);
    scan_final<<<SCAN_NB, SCAN_BS, 0, stream>>>(cnt, bsum, cursor);
    bucket_fill<<<(EE + 255) / 256, 256, 0, stream>>>(src, dst, et, cursor, esrc);

    const int MT = (NN + 127) / 128;      // 391

    // ---- layer 1: ONE fused GEMM (8 rels -> xWall fp16, root+bias -> h_pre fp32) ----
    gemm16<CIN, CIN, CIN, CIN, N1, 4><<<MT * (N1 / 128), 256, 0, stream>>>(
        x16, x16, W1c, h_pre, b1, xWall, NN);
    // ---- ONE gather: hh = relu(h_pre + sum_rel mean(xWall)) ----
    gather_l1<<<(NN + 3) / 4, 256, 0, stream>>>(xWall, esrc, cursor, cnt, h_pre, hh);

    // ---- layer 2: ONE gather (G2 full-N) + ONE K=2304 GEMM ----
    gather_g2<<<(SEGS + 3) / 4, 256, 0, stream>>>(hh, esrc, cursor, cnt, G2);
    gemm16<K2, K2S, K2S, CHID, COUT, 3><<<MT * (COUT / 128), 256, 0, stream>>>(
        G2, hh, W2c, out, b2, nullptr, NN);

    l2norm<<<(NN + 3) / 4, 256, 0, stream>>>(out);
}